// Round 3
// baseline (339.895 us; speedup 1.0000x reference)
//
#include <hip/hip_runtime.h>

// BERTEmbedding: out[b,v,e] = (s0*flux_w[v,e] + flux_b[v,e])
//                           + (s2*time_w[v,e] + time_b[v,e])
//                           + PE(s1)[e]   (interleaved sin/cos)
// B=16, V=4096, E=768, fp32.
//
// R3 layout: one thread per (b, v, e4) output float4; out index == tid*4, so
// the store stream is monotone sequential across the dispatch — exactly the
// shape of the harness fill that measures 6.5 TB/s. Weight reuse (16x) is
// delegated to the 256 MiB Infinity Cache (weights total 50.3 MB): b-major
// block order lets the b=0 slab fetch them from HBM once, slabs 1..15 hit L3.
#define BB 16
#define VV 4096
#define EE 768
#define E4 (EE / 4)   // 192 float4 columns per row

typedef float f4 __attribute__((ext_vector_type(4)));

__global__ __launch_bounds__(256) void bert_embed_kernel(
    const float* __restrict__ seq,     // [B, V, 3]
    const float* __restrict__ flux_w,  // [V, E]
    const float* __restrict__ flux_b,  // [V, E]
    const float* __restrict__ time_w,  // [V, E]
    const float* __restrict__ time_b,  // [V, E]
    float* __restrict__ out)           // [B, V, E]
{
    int tid = blockIdx.x * blockDim.x + threadIdx.x;   // [0, BB*VV*E4)
    int e4  = tid % E4;
    // 192 threads per (b,v) row = exactly 3 waves -> (b*V+v) is wave-uniform;
    // force scalar so the 3 sequence loads become s_loads through K$.
    int bv  = __builtin_amdgcn_readfirstlane(tid / E4);   // b*VV + v
    int v   = bv & (VV - 1);

    const size_t we = (size_t)v * EE + (size_t)e4 * 4;
    f4 fw = *(const f4*)(flux_w + we);   // L3-resident after first slab
    f4 tw = *(const f4*)(time_w + we);
    f4 fb = *(const f4*)(flux_b + we);
    f4 tb = *(const f4*)(time_b + we);

    // div_term[i] = exp(2i * (-ln(10000)/E)); pair indices 2*e4, 2*e4+1.
    // 1/(2*pi) folded in: v_sin_f32/v_cos_f32 take REVOLUTIONS (cdna4_isa §3);
    // |s1*d| < ~1 rev, inside the accurate range.
    const float C1     = -0.011992630692677323f;   // -ln(10000)/768
    const float INV2PI = 0.15915494309189535f;
    float d0 = __expf((float)(4 * e4) * C1) * INV2PI;
    float d1 = __expf((float)(4 * e4 + 2) * C1) * INV2PI;

    const float* sp = seq + (size_t)bv * 3;   // wave-uniform address
    float s0 = sp[0];   // flux channel
    float s1 = sp[1];   // passend channel
    float s2 = sp[2];   // time channel

    float r0 = s1 * d0;
    float r1 = s1 * d1;

    f4 o;
    o.x = fmaf(s0, fw.x, fb.x) + fmaf(s2, tw.x, tb.x) + __builtin_amdgcn_sinf(r0);
    o.y = fmaf(s0, fw.y, fb.y) + fmaf(s2, tw.y, tb.y) + __builtin_amdgcn_cosf(r0);
    o.z = fmaf(s0, fw.z, fb.z) + fmaf(s2, tw.z, tb.z) + __builtin_amdgcn_sinf(r1);
    o.w = fmaf(s0, fw.w, fb.w) + fmaf(s2, tw.w, tb.w) + __builtin_amdgcn_cosf(r1);

    // out index = tid*4: perfectly sequential store stream. Nontemporal so
    // the 201 MB output doesn't evict the 50 MB weight set from L3.
    __builtin_nontemporal_store(o, (f4*)(out + (size_t)tid * 4));
}

extern "C" void kernel_launch(void* const* d_in, const int* in_sizes, int n_in,
                              void* d_out, int out_size, void* d_ws, size_t ws_size,
                              hipStream_t stream) {
    const float* seq = (const float*)d_in[0];
    const float* fw  = (const float*)d_in[1];
    const float* fb  = (const float*)d_in[2];
    const float* tw  = (const float*)d_in[3];
    const float* tb  = (const float*)d_in[4];
    float* out = (float*)d_out;

    const int total_threads = BB * VV * E4;   // 12,582,912
    const int block = 256;
    const int grid  = total_threads / block;  // 49,152 blocks

    bert_embed_kernel<<<grid, block, 0, stream>>>(seq, fw, fb, tw, tb, out);
}